// Round 6
// baseline (142.640 us; speedup 1.0000x reference)
//
#include <hip/hip_runtime.h>

#define HH 512
#define WW 1024
#define NC 19
#define HWP (HH * WW)
#define NB 4
#define NREP 4
#define NXCD 8
#define IGNORE_IDX 255
#define RECB 48   // bytes per pixel record: 24 x fp16 (19 used)

typedef float f2v __attribute__((ext_vector_type(2)));
typedef float f4v __attribute__((ext_vector_type(4)));
typedef _Float16 h16;

union Rec { f4v v[3]; h16 h[24]; };

// ---- Pass 1: coalesced preds softmax -> pixel-major fp16 records ----
__global__ __launch_bounds__(256) void tc_prep(
    const float* __restrict__ preds, char* __restrict__ P)
{
    const int t = blockIdx.x * 256 + threadIdx.x;   // 2 px per thread
    const int pix2 = t * 2;
    const int b   = pix2 >> 19;          // HWP = 524288
    const int pix = pix2 & (HWP - 1);
    const float* pb = preds + (size_t)b * NC * HWP + pix;

    float e0[NC], e1[NC];
    float s0 = 0.f, s1 = 0.f;
#pragma unroll
    for (int c = 0; c < NC; ++c) {
        const f2v v = __builtin_nontemporal_load((const f2v*)(pb + (size_t)c * HWP));
        e0[c] = __expf(v.x); s0 += e0[c];
        e1[c] = __expf(v.y); s1 += e1[c];
    }
    const float i0 = 1.f / s0, i1 = 1.f / s1;

    const f4v zero = {0.f, 0.f, 0.f, 0.f};
    Rec r0, r1;
#pragma unroll
    for (int i = 0; i < 3; ++i) { r0.v[i] = zero; r1.v[i] = zero; }
#pragma unroll
    for (int c = 0; c < NC; ++c) {
        r0.h[c] = (h16)(e0[c] * i0);
        r1.h[c] = (h16)(e1[c] * i1);
    }
    f4v* out = (f4v*)(P + (size_t)pix2 * RECB);   // 96B contiguous per thread
    out[0] = r0.v[0]; out[1] = r0.v[1]; out[2] = r0.v[2];
    out[3] = r1.v[0]; out[4] = r1.v[1]; out[5] = r1.v[2];
}

// ---- Pass 2: targets softmax + compact record gather + fuzzy IoU ----
__global__ __launch_bounds__(256) void tc_main_p(
    const char* __restrict__ P,
    const float* __restrict__ targets,
    const float* __restrict__ flow,
    const int* __restrict__ labels,
    float* __restrict__ acc)
{
    const int tid = threadIdx.x;

    // XCD-chunked swizzle (R4 win: overlapping gather rows share one L2)
    const int nwg   = gridDim.x;              // 2048
    const int chunk = nwg / NXCD;             // 256
    const int phys  = blockIdx.x;
    const int logical = (phys % NXCD) * chunk + phys / NXCD;

    const int blocks_per_img = nwg / NB;      // 512
    const int b   = logical / blocks_per_img;
    const int blk = logical % blocks_per_img;

    float accn[NC], accd[NC];
#pragma unroll
    for (int c = 0; c < NC; ++c) { accn[c] = 0.f; accd[c] = 0.f; }

    const float* tb = targets + (size_t)b * NC * HWP;
    const char*  Pb = P + (size_t)b * HWP * RECB;
    const f2v*   fb = (const f2v*)(flow + (size_t)b * HWP * 2);
    const int*   lb = labels + (size_t)b * HWP;

    const int per_block = HWP / blocks_per_img;   // 1024 (one image row)
    const int base = blk * per_block;

    for (int k = tid; k < per_block; k += 256) {
        const int pix = base + k;
        const int y = pix >> 10;       // WW = 1024
        const int x = pix & (WW - 1);

        const f2v f = __builtin_nontemporal_load(&fb[pix]);
        const int rx = (int)rintf((float)x + f.x);   // half-even == jnp.round
        const int ry = (int)rintf((float)y + f.y);
        const bool valid = (rx >= 0) && (rx < WW) && (ry >= 0) && (ry < HH);
        const int spix = min(max(ry, 0), HH - 1) * WW + min(max(rx, 0), WW - 1);
        const bool keep = (__builtin_nontemporal_load(&lb[pix]) != IGNORE_IDX);

        // warped preds softmax: one 48B record, 3 x dwordx4
        Rec r;
        const f4v* rec = (const f4v*)(Pb + (size_t)spix * RECB);
        r.v[0] = rec[0]; r.v[1] = rec[1]; r.v[2] = rec[2];
        const float validf = valid ? 1.f : 0.f;

        // targets softmax (streaming)
        float te[NC];
        float tsum = 0.f;
#pragma unroll
        for (int c = 0; c < NC; ++c) {
            te[c] = __expf(__builtin_nontemporal_load(&tb[(size_t)c * HWP + pix]));
            tsum += te[c];
        }
        const float tinv = keep ? (1.0f / tsum) : 0.0f;

#pragma unroll
        for (int c = 0; c < NC; ++c) {
            const float t = te[c] * tinv;
            const float p = (float)r.h[c] * validf;
            const float pt = p * t;
            accn[c] += pt;
            accd[c] += p + t - pt;
        }
    }

#pragma unroll
    for (int c = 0; c < NC; ++c) {
        for (int off = 32; off > 0; off >>= 1) {
            accn[c] += __shfl_xor(accn[c], off);
            accd[c] += __shfl_xor(accd[c], off);
        }
    }

    __shared__ float s[4][NC][2];
    const int wave = tid >> 6;
    const int lane = tid & 63;
    if (lane == 0) {
#pragma unroll
        for (int c = 0; c < NC; ++c) {
            s[wave][c][0] = accn[c];
            s[wave][c][1] = accd[c];
        }
    }
    __syncthreads();
    if (tid < NC * 2) {
        const int c = tid >> 1;
        const int which = tid & 1;
        const float v = s[0][c][which] + s[1][c][which] + s[2][c][which] + s[3][c][which];
        const int rep = phys & (NREP - 1);
        atomicAdd(&acc[(((size_t)rep * NB + b) * NC + c) * 2 + which], v);
    }
}

// ---- Fallback (R4 kernel) if ws_size can't hold the 96MB record buffer ----
__global__ __launch_bounds__(256) void tc_main_direct(
    const float* __restrict__ preds,
    const float* __restrict__ targets,
    const float* __restrict__ flow,
    const int* __restrict__ labels,
    float* __restrict__ acc)
{
    const int tid = threadIdx.x;
    const int nwg   = gridDim.x;
    const int chunk = nwg / NXCD;
    const int phys  = blockIdx.x;
    const int logical = (phys % NXCD) * chunk + phys / NXCD;
    const int blocks_per_img = nwg / NB;
    const int b   = logical / blocks_per_img;
    const int blk = logical % blocks_per_img;

    float accn[NC], accd[NC];
#pragma unroll
    for (int c = 0; c < NC; ++c) { accn[c] = 0.f; accd[c] = 0.f; }

    const float* tb = targets + (size_t)b * NC * HWP;
    const float* pb = preds   + (size_t)b * NC * HWP;
    const f2v*   fb = (const f2v*)(flow + (size_t)b * HWP * 2);
    const int*   lb = labels  + (size_t)b * HWP;

    const int per_block = HWP / blocks_per_img;
    const int base = blk * per_block;

    for (int k = tid; k < per_block; k += 256) {
        const int pix = base + k;
        const int y = pix >> 10;
        const int x = pix & (WW - 1);
        const f2v f = __builtin_nontemporal_load(&fb[pix]);
        const int rx = (int)rintf((float)x + f.x);
        const int ry = (int)rintf((float)y + f.y);
        const bool valid = (rx >= 0) && (rx < WW) && (ry >= 0) && (ry < HH);
        const int spix = min(max(ry, 0), HH - 1) * WW + min(max(rx, 0), WW - 1);
        const bool keep = (__builtin_nontemporal_load(&lb[pix]) != IGNORE_IDX);

        float te[NC], pe[NC];
        float tsum = 0.f, psum = 0.f;
#pragma unroll
        for (int c = 0; c < NC; ++c) {
            te[c] = __expf(__builtin_nontemporal_load(&tb[(size_t)c * HWP + pix]));
            tsum += te[c];
        }
#pragma unroll
        for (int c = 0; c < NC; ++c) {
            pe[c] = __expf(pb[(size_t)c * HWP + spix]);
            psum += pe[c];
        }
        const float tinv = keep  ? (1.0f / tsum) : 0.0f;
        const float pinv = valid ? (1.0f / psum) : 0.0f;
#pragma unroll
        for (int c = 0; c < NC; ++c) {
            const float t = te[c] * tinv;
            const float p = pe[c] * pinv;
            const float pt = p * t;
            accn[c] += pt;
            accd[c] += p + t - pt;
        }
    }

#pragma unroll
    for (int c = 0; c < NC; ++c) {
        for (int off = 32; off > 0; off >>= 1) {
            accn[c] += __shfl_xor(accn[c], off);
            accd[c] += __shfl_xor(accd[c], off);
        }
    }
    __shared__ float s[4][NC][2];
    const int wave = tid >> 6;
    const int lane = tid & 63;
    if (lane == 0) {
#pragma unroll
        for (int c = 0; c < NC; ++c) { s[wave][c][0] = accn[c]; s[wave][c][1] = accd[c]; }
    }
    __syncthreads();
    if (tid < NC * 2) {
        const int c = tid >> 1;
        const int which = tid & 1;
        const float v = s[0][c][which] + s[1][c][which] + s[2][c][which] + s[3][c][which];
        const int rep = phys & (NREP - 1);
        atomicAdd(&acc[(((size_t)rep * NB + b) * NC + c) * 2 + which], v);
    }
}

__global__ void tc_final(const float* __restrict__ acc, float* __restrict__ out)
{
    if (threadIdx.x == 0 && blockIdx.x == 0) {
        float total = 0.f;
        for (int b = 0; b < NB; ++b) {
            float m = 0.f;
            for (int c = 0; c < NC; ++c) {
                float n = 0.f, d = 0.f;
                for (int r = 0; r < NREP; ++r) {
                    n += acc[(((size_t)r * NB + b) * NC + c) * 2 + 0];
                    d += acc[(((size_t)r * NB + b) * NC + c) * 2 + 1];
                }
                m += n / d;
            }
            total += 1.0f - m / (float)NC;
        }
        out[0] = total / (float)NB;
    }
}

extern "C" void kernel_launch(void* const* d_in, const int* in_sizes, int n_in,
                              void* d_out, int out_size, void* d_ws, size_t ws_size,
                              hipStream_t stream) {
    const float* preds   = (const float*)d_in[0];
    const float* targets = (const float*)d_in[1];
    const float* flow    = (const float*)d_in[2];
    const int*   labels  = (const int*)d_in[3];
    float* acc = (float*)d_ws;

    hipMemsetAsync(acc, 0, (size_t)NREP * NB * NC * 2 * sizeof(float), stream);

    const size_t pbytes = (size_t)NB * HWP * RECB;   // ~96 MB
    const size_t need   = 1024 + pbytes;

    if (ws_size >= need) {
        char* P = (char*)d_ws + 1024;
        tc_prep<<<(NB * HWP / 2) / 256, 256, 0, stream>>>(preds, P);
        tc_main_p<<<2048, 256, 0, stream>>>(P, targets, flow, labels, acc);
    } else {
        tc_main_direct<<<2048, 256, 0, stream>>>(preds, targets, flow, labels, acc);
    }
    tc_final<<<1, 64, 0, stream>>>(acc, (float*)d_out);
}

// Round 7
// 114.922 us; speedup vs baseline: 1.2412x; 1.2412x over previous
//
#include <hip/hip_runtime.h>

#define HH 512
#define WW 1024
#define NC 19
#define HWP (HH * WW)
#define NB 4
#define NREP 4
#define NXCD 8
#define IGNORE_IDX 255
#define TRW 32   // tile rows
#define TCL 16   // tile cols

typedef float f2v __attribute__((ext_vector_type(2)));

__device__ __forceinline__ unsigned pack_h2(float a, float b) {
    unsigned short lo = __builtin_bit_cast(unsigned short, (_Float16)a);
    unsigned short hi = __builtin_bit_cast(unsigned short, (_Float16)b);
    return (unsigned)lo | ((unsigned)hi << 16);
}
__device__ __forceinline__ float unpack_h2(unsigned v, int j) {
    unsigned short u = (unsigned short)(j ? (v >> 16) : (v & 0xffff));
    return (float)__builtin_bit_cast(_Float16, u);
}

// ws layout: float acc[NREP][NB][NC][2]  (num, den)
__global__ __launch_bounds__(256) void tc_main(
    const float* __restrict__ preds,
    const float* __restrict__ targets,
    const float* __restrict__ flow,
    const int* __restrict__ labels,
    float* __restrict__ acc)
{
    const int tid = threadIdx.x;

    // XCD-chunked swizzle; logical order = row-major tiles so vertical halo
    // neighbors (tile row +-1) stay in the same XCD's L2.
    const int nwg   = gridDim.x;            // 4096
    const int chunk = nwg / NXCD;           // 512
    const int phys  = blockIdx.x;
    const int logical = (phys % NXCD) * chunk + phys / NXCD;

    const int b   = logical >> 10;          // 1024 tiles per image
    const int il  = logical & 1023;
    const int tr  = il >> 6;                // 16 tile-rows  (512/32)
    const int tc  = il & 63;                // 64 tile-cols  (1024/16)
    const int row0 = tr * TRW;
    const int col0 = tc * TCL;

    const float* tb = targets + (size_t)b * NC * HWP;
    const float* pb = preds   + (size_t)b * NC * HWP;
    const f2v*   fb = (const f2v*)(flow + (size_t)b * HWP * 2);
    const int*   lb = labels  + (size_t)b * HWP;

    // ---- Phase A: per-thread 2 pixels -> warped source index + masks ----
    int   sp[2];    // clipped source pixel
    float vf[2];    // valid ? 1 : 0
    int   pixg[2];  // own pixel index

#pragma unroll
    for (int j = 0; j < 2; ++j) {
        const int pi  = j * 256 + tid;          // 0..511
        const int r   = row0 + (pi >> 4);       // 4 rows per wave
        const int c_  = col0 + (pi & (TCL - 1));
        const int pix = r * WW + c_;
        pixg[j] = pix;

        const f2v f = __builtin_nontemporal_load(&fb[pix]);
        const int rx = (int)rintf((float)c_ + f.x);  // half-even == jnp.round
        const int ry = (int)rintf((float)r  + f.y);
        const bool valid = (rx >= 0) && (rx < WW) && (ry >= 0) && (ry < HH);
        sp[j] = min(max(ry, 0), HH - 1) * WW + min(max(rx, 0), WW - 1);
        vf[j] = valid ? 1.f : 0.f;
    }

    // ---- Phase B: channel-major gather + exp, packed fp16 in registers ----
    // Per channel the block touches ~6KB (40 rows x ~24 cols) -> L1-resident,
    // so the block's 8 gather instructions per channel hit L1 after first touch.
    float psum0 = 0.f, psum1 = 0.f;
    unsigned pe2[NC];
#pragma unroll
    for (int c = 0; c < NC; ++c) {
        const float e0 = __expf(pb[(size_t)c * HWP + sp[0]]);
        const float e1 = __expf(pb[(size_t)c * HWP + sp[1]]);
        psum0 += e0;
        psum1 += e1;
        pe2[c] = pack_h2(e0, e1);
    }
    const float pinv[2] = { vf[0] / psum0, vf[1] / psum1 };

    // ---- Phase C: targets softmax (streaming) + fuzzy IoU accumulate ----
    float accn[NC], accd[NC];
#pragma unroll
    for (int c = 0; c < NC; ++c) { accn[c] = 0.f; accd[c] = 0.f; }

#pragma unroll
    for (int j = 0; j < 2; ++j) {
        const int pix = pixg[j];
        const bool keep = (__builtin_nontemporal_load(&lb[pix]) != IGNORE_IDX);

        float te[NC];
        float tsum = 0.f;
#pragma unroll
        for (int c = 0; c < NC; ++c) {
            te[c] = __expf(__builtin_nontemporal_load(&tb[(size_t)c * HWP + pix]));
            tsum += te[c];
        }
        const float tinv = keep ? (1.0f / tsum) : 0.0f;
        const float pv   = pinv[j];

#pragma unroll
        for (int c = 0; c < NC; ++c) {
            const float t = te[c] * tinv;
            const float p = unpack_h2(pe2[c], j) * pv;
            const float pt = p * t;
            accn[c] += pt;
            accd[c] += p + t - pt;
        }
    }

    // ---- reduction: wave shuffle -> LDS -> one atomic per value ----
#pragma unroll
    for (int c = 0; c < NC; ++c) {
        for (int off = 32; off > 0; off >>= 1) {
            accn[c] += __shfl_xor(accn[c], off);
            accd[c] += __shfl_xor(accd[c], off);
        }
    }

    __shared__ float s[4][NC][2];
    const int wave = tid >> 6;
    const int lane = tid & 63;
    if (lane == 0) {
#pragma unroll
        for (int c = 0; c < NC; ++c) {
            s[wave][c][0] = accn[c];
            s[wave][c][1] = accd[c];
        }
    }
    __syncthreads();
    if (tid < NC * 2) {
        const int c = tid >> 1;
        const int which = tid & 1;
        const float v = s[0][c][which] + s[1][c][which] + s[2][c][which] + s[3][c][which];
        const int rep = phys & (NREP - 1);
        atomicAdd(&acc[(((size_t)rep * NB + b) * NC + c) * 2 + which], v);
    }
}

__global__ void tc_final(const float* __restrict__ acc, float* __restrict__ out)
{
    if (threadIdx.x == 0 && blockIdx.x == 0) {
        float total = 0.f;
        for (int b = 0; b < NB; ++b) {
            float m = 0.f;
            for (int c = 0; c < NC; ++c) {
                float n = 0.f, d = 0.f;
                for (int r = 0; r < NREP; ++r) {
                    n += acc[(((size_t)r * NB + b) * NC + c) * 2 + 0];
                    d += acc[(((size_t)r * NB + b) * NC + c) * 2 + 1];
                }
                m += n / d;
            }
            total += 1.0f - m / (float)NC;
        }
        out[0] = total / (float)NB;
    }
}

extern "C" void kernel_launch(void* const* d_in, const int* in_sizes, int n_in,
                              void* d_out, int out_size, void* d_ws, size_t ws_size,
                              hipStream_t stream) {
    const float* preds   = (const float*)d_in[0];
    const float* targets = (const float*)d_in[1];
    const float* flow    = (const float*)d_in[2];
    const int*   labels  = (const int*)d_in[3];
    float* acc = (float*)d_ws;

    hipMemsetAsync(acc, 0, (size_t)NREP * NB * NC * 2 * sizeof(float), stream);

    tc_main<<<4096, 256, 0, stream>>>(preds, targets, flow, labels, acc);
    tc_final<<<1, 64, 0, stream>>>(acc, (float*)d_out);
}